// Round 12
// baseline (319.360 us; speedup 1.0000x reference)
//
#include <hip/hip_runtime.h>
#include <math.h>

#define NPTS 8192
#define NB   4
#define KNN  16
#define NC   64
#define NQ   (NB * NPTS)   // 32768 total queries
#define CAP2 32            // per-(wave,query) LDS survivor capacity
#define SEGCAP 64          // per-(query,cgroup) global survivor segment

// ---------------------------------------------------------------------------
// prep (2 phases as separate blocks) — EXACT r2/r10 revert (validated):
//  phase 0 (source pts): cand[b][m]=(x,y,z,|p|^2); GF[b][m][o]=(Gk,F2)
//  phase 1 (center pts): CF[b][n][o]=(Gc+bg, F1+bf)
// [r11 post-mortem: 2-pt/thread variant hit 256 VGPR -> scratch spill ->
//  VALUBusy 0.09%, 70-96us. Reverted.]
// ---------------------------------------------------------------------------
__global__ __launch_bounds__(256) void prep_kernel(
    const float* __restrict__ xyz, const float* __restrict__ xyz_s,
    const float* __restrict__ fea, const float* __restrict__ fea_s,
    const float* __restrict__ Wg,  const float* __restrict__ bg,
    const float* __restrict__ Wf,  const float* __restrict__ bf,
    float4* __restrict__ cand, float2* __restrict__ GF, float2* __restrict__ CF)
{
    __shared__ float wt[64 * 64];
    __shared__ float gw[3 * 64];
    __shared__ float bias2[2 * 64];
    int tid   = threadIdx.x;
    int phase = blockIdx.x & 1;
    int g     = (blockIdx.x >> 1) * 256 + tid;
    int b     = g >> 13, m = g & (NPTS - 1);

    for (int i = tid; i < 4096; i += 256) {
        int o = i >> 6, c = i & 63;
        wt[c * 64 + o] = Wf[o * 128 + (phase ? c : 64 + c)];
    }
    if (tid < 192) {
        int d = tid >> 6, o = tid & 63;
        gw[d * 64 + o] = phase ? (Wg[o * 10 + 1 + d] + Wg[o * 10 + 7 + d])
                               : (Wg[o * 10 + 4 + d] - Wg[o * 10 + 7 + d]);
    }
    if (tid < 64) {
        bias2[tid]      = phase ? bg[tid] : 0.f;
        bias2[64 + tid] = phase ? bf[tid] : 0.f;
    }
    __syncthreads();

    const float* P = phase ? xyz : xyz_s;
    const float* F = phase ? fea : fea_s;
    float x = P[(b * 3 + 0) * NPTS + m];
    float y = P[(b * 3 + 1) * NPTS + m];
    float z = P[(b * 3 + 2) * NPTS + m];
    if (!phase) cand[b * NPTS + m] = make_float4(x, y, z, x * x + y * y + z * z);

    float acc[NC];
    #pragma unroll
    for (int o = 0; o < NC; o++) acc[o] = 0.f;
    for (int c = 0; c < NC; c++) {
        float v = F[(size_t)(b * NC + c) * NPTS + m];
        const float4* w4 = (const float4*)&wt[c * 64];
        #pragma unroll
        for (int o4 = 0; o4 < 16; o4++) {
            float4 w = w4[o4];
            acc[o4*4+0] = fmaf(w.x, v, acc[o4*4+0]);
            acc[o4*4+1] = fmaf(w.y, v, acc[o4*4+1]);
            acc[o4*4+2] = fmaf(w.z, v, acc[o4*4+2]);
            acc[o4*4+3] = fmaf(w.w, v, acc[o4*4+3]);
        }
    }
    float2* O = (phase ? CF : GF) + ((size_t)(b * NPTS + m)) * NC;
    #pragma unroll
    for (int o = 0; o < NC; o++) {
        float geo = fmaf(gw[o], x, fmaf(gw[64 + o], y, gw[128 + o] * z));
        O[o] = make_float2(geo + bias2[o], acc[o] + bias2[64 + o]);
    }
}

// ---------------------------------------------------------------------------
// knn_tau: per query, tau = 16th largest of 32 slice-maxima (32 disjoint
// slices of 128 over the first 4096 candidates -> >=16 witnesses >= tau).
// [r11 post-mortem: batch-of-8 uniform loads were re-serialized by the
//  compiler (VGPR=36 proves it kept <=2 in flight) -> still latency-bound at
//  70us. New score phase: COALESCED per-lane loads (8 per wave total) +
//  register broadcast via compile-time __shfl — no memory pipe in the inner
//  loop at all. fmax is exactly associative, candidate bits and fma nesting
//  unchanged -> slice maxima bit-identical -> tau bit-identical.]
// Wave w covers candidates [512w, 512w+512) = slices [4w, 4w+4).
// Selection: cross-lane bitonic (r9-validated, shuffle outside branch).
// Writes QT[q] = (2x, 2y, 2z, tau).
// ---------------------------------------------------------------------------
__global__ __launch_bounds__(512) void knn_tau(
    const float4* __restrict__ cand, const float* __restrict__ xyz,
    float4* __restrict__ QT)
{
    __shared__ float mx[64][33];
    __shared__ float tauL[64];
    int tid = threadIdx.x;
    int lane = tid & 63, w = tid >> 6;         // w in 0..7
    int bid = blockIdx.x;
    int b = bid >> 7;                          // 128 blocks per batch
    int qb = (bid & 127) * 64;

    int q = qb + lane;
    float qx = xyz[(b * 3 + 0) * NPTS + q];
    float qy = xyz[(b * 3 + 1) * NPTS + q];
    float qz = xyz[(b * 3 + 2) * NPTS + q];
    float ax = 2.f * qx, ay = 2.f * qy, az = 2.f * qz;

    const float4* cb = cand + b * NPTS;
    for (int i = 0; i < 4; i++) {              // slice i of this wave
        float mm = -3.0e38f;
        for (int h = 0; h < 2; h++) {          // two 64-cand groups per slice
            float4 c = cb[w * 512 + i * 128 + h * 64 + lane];  // coalesced
            #pragma unroll
            for (int j = 0; j < 64; j++) {     // broadcast cand j to all lanes
                float cx = __shfl(c.x, j);
                float cy = __shfl(c.y, j);
                float cz = __shfl(c.z, j);
                float cw = __shfl(c.w, j);
                float sc = fmaf(cx, ax, fmaf(cy, ay, fmaf(cz, az, -cw)));
                mm = fmaxf(mm, sc);
            }
        }
        mx[lane][w * 4 + i] = mm;
    }
    __syncthreads();

    // cross-lane selection: wave w -> queries [8w, 8w+8); ALL lanes run the
    // shuffle network, only the store is predicated.
    for (int qq = w * 8; qq < w * 8 + 8; ++qq) {
        float v = (lane < 32) ? mx[qq][lane] : -3.0e38f;
        #pragma unroll
        for (int k = 2; k <= 64; k <<= 1) {
            #pragma unroll
            for (int j = k >> 1; j > 0; j >>= 1) {
                float o = __shfl_xor(v, j);
                bool up = ((lane & k) == 0);
                bool lower = ((lane & j) == 0);
                v = (up == lower) ? fminf(v, o) : fmaxf(v, o);
            }
        }
        float t = __shfl(v, 48);               // 16th largest (all lanes)
        if (lane == 0) tauL[qq] = t;
    }
    __syncthreads();

    if (tid < 64) {
        int q2 = qb + tid;
        float x = xyz[(b * 3 + 0) * NPTS + q2];
        float y = xyz[(b * 3 + 1) * NPTS + q2];
        float z = xyz[(b * 3 + 2) * NPTS + q2];
        QT[b * NPTS + q2] = make_float4(2.f * x, 2.f * y, 2.f * z, tauL[tid]);
    }
}

// ---------------------------------------------------------------------------
// knn_scan — unchanged (validated r11): 64 queries/block, candidate-
// stationary registers, zero global atomics, QT prefetch x4, wave-private
// LDS survivor lists, one coalesced flush per block.
// Grid: NB * 128(qchunk of 64 queries) * 4(cgroup of 2048 cands) = 2048.
// ---------------------------------------------------------------------------
__global__ __launch_bounds__(256) void knn_scan(
    const float4* __restrict__ cand, const float4* __restrict__ QT,
    unsigned short* __restrict__ surv2, unsigned char* __restrict__ cnt2)
{
    __shared__ unsigned short wl[4][64][CAP2];    // 16 KB
    __shared__ unsigned char  wcnt[4][64];

    int tid = threadIdx.x;
    int lane = tid & 63, w = tid >> 6;
    int bid = blockIdx.x;
    int b = bid >> 9;               // 512 blocks per batch
    int r = bid & 511;
    int qc = r >> 2;                // 128 query-chunks of 64
    int cg = r & 3;
    int cchunk = cg * 4 + w;        // 16 candidate-chunks of 512
    int ci0 = cchunk * 512 + lane;
    const float4* cb = cand + b * NPTS;

    float4 c[8];
    #pragma unroll
    for (int s = 0; s < 8; s++) c[s] = cb[ci0 + (s << 6)];

    int qbase = b * NPTS + qc * 64;
    unsigned long long lmask = (1ull << lane) - 1ull;

    float4 qtc[4], qtn[4];
    #pragma unroll
    for (int u = 0; u < 4; u++) qtc[u] = QT[qbase + u];

    for (int qi0 = 0; qi0 < 64; qi0 += 4) {
        if (qi0 + 4 < 64) {
            #pragma unroll
            for (int u = 0; u < 4; u++) qtn[u] = QT[qbase + qi0 + 4 + u];
        }
        #pragma unroll
        for (int u = 0; u < 4; u++) {
            int qi = qi0 + u;
            float4 qt = qtc[u];
            unsigned vcnt = 0;
            #pragma unroll
            for (int s = 0; s < 8; s++) {
                float sc = fmaf(c[s].x, qt.x,
                           fmaf(c[s].y, qt.y,
                           fmaf(c[s].z, qt.z, -c[s].w)));
                bool p = (sc >= qt.w);
                unsigned long long mask = __ballot(p);
                if (p) {
                    unsigned pos = vcnt + (unsigned)__popcll(mask & lmask);
                    if (pos < CAP2)
                        wl[w][qi][pos] = (unsigned short)(ci0 + (s << 6));
                }
                vcnt += (unsigned)__popcll(mask);
            }
            if (lane == 0)
                wcnt[w][qi] = (unsigned char)(vcnt < CAP2 ? vcnt : CAP2);
        }
        #pragma unroll
        for (int u = 0; u < 4; u++) qtc[u] = qtn[u];
    }
    __syncthreads();

    // flush: thread = query; concatenate 4 wave-lists -> global segment
    if (tid < 64) {
        int qi = tid;
        int col = qbase + qi;
        unsigned short* dst = surv2 + ((size_t)col * 4 + cg) * SEGCAP;
        unsigned tot = 0;
        #pragma unroll
        for (int w2 = 0; w2 < 4; w2++) {
            int cw = wcnt[w2][qi];
            for (int j = 0; j < cw; j++) {
                if (tot < SEGCAP) dst[tot] = wl[w2][qi][j];
                tot++;
            }
        }
        cnt2[(size_t)col * 4 + cg] =
            (unsigned char)(tot < SEGCAP ? tot : SEGCAP);
    }
}

// ---------------------------------------------------------------------------
// knn_select — unchanged (validated r7..r11): thread per query; re-score
// survivors exactly, keep top-16 via sorted u64 keys (order-independent);
// tie -> smaller index (matches jax top_k).
// ---------------------------------------------------------------------------
__global__ __launch_bounds__(256) void knn_select(
    const float4* __restrict__ cand, const float4* __restrict__ QT,
    const uchar4* __restrict__ cnt2, const unsigned short* __restrict__ surv2,
    int* __restrict__ idxout)
{
    int g = blockIdx.x * 256 + threadIdx.x;    // global query id
    int b = g >> 13;
    float4 qt = QT[g];
    uchar4 cc = cnt2[g];
    int cnts[4] = { cc.x, cc.y, cc.z, cc.w };
    const float4* cb = cand + b * NPTS;
    const unsigned short* sp = surv2 + (size_t)g * 4 * SEGCAP;

    unsigned long long s[KNN];
    #pragma unroll
    for (int j = 0; j < KNN; j++) s[j] = 0ull;

    for (int cg = 0; cg < 4; cg++) {
        int cn = cnts[cg];
        const unsigned short* spc = sp + cg * SEGCAP;
        for (int j0 = 0; j0 < cn; j0 += 4) {
            int li[4];
            float4 cd[4];
            #pragma unroll
            for (int t = 0; t < 4; t++) {
                int j = j0 + t;
                li[t] = (j < cn) ? (int)spc[j] : -1;
            }
            #pragma unroll
            for (int t = 0; t < 4; t++)
                if (li[t] >= 0) cd[t] = cb[li[t]];
            #pragma unroll
            for (int t = 0; t < 4; t++) {
                if (li[t] < 0) continue;
                float sc = fmaf(cd[t].x, qt.x,
                           fmaf(cd[t].y, qt.y,
                           fmaf(cd[t].z, qt.z, -cd[t].w)));
                unsigned u = __float_as_uint(sc);
                u ^= (unsigned)((int)u >> 31) | 0x80000000u;
                unsigned long long key =
                    ((unsigned long long)u << 32) | (unsigned)(8191 - li[t]);
                if (key > s[0]) {
                    bool cj = true;
                    #pragma unroll
                    for (int t2 = 0; t2 < KNN; t2++) {
                        bool cn2 = (t2 < KNN - 1) ? (key > s[t2 + 1]) : false;
                        unsigned long long fv = cj ? key : s[t2];
                        s[t2] = cn2 ? s[t2 + 1] : fv;
                        cj = cn2;
                    }
                }
            }
        }
    }
    int* op = idxout + ((size_t)g << 4);
    #pragma unroll
    for (int j = 0; j < KNN; j++)
        op[j] = 8191 - (int)(s[j] & 0xFFFFFFFFull);
}

// ---------------------------------------------------------------------------
// fuse — unchanged (validated r2..r11):
// out[b][o][n] = max_k relu(CF.x + wd*d + GF.x) * relu(CF.y + GF.y)
// ---------------------------------------------------------------------------
__global__ __launch_bounds__(256) void fuse_kernel(
    const float* __restrict__ xyz, const float* __restrict__ Wg,
    const float4* __restrict__ cand, const float2* __restrict__ GF,
    const float2* __restrict__ CF, const int* __restrict__ idxb,
    float* __restrict__ out)
{
    __shared__ float tile[16 * 65];
    int tid = threadIdx.x;
    int o = tid & 63, w = tid >> 6;
    int b = blockIdx.x >> 9;
    int nt = (blockIdx.x & 511) << 4;
    float wd = Wg[o * 10];

    for (int i = 0; i < 4; i++) {
        int q = nt + w * 4 + i;
        size_t qb = (size_t)(b * NPTS + q);
        float qx = xyz[(b * 3 + 0) * NPTS + q];
        float qy = xyz[(b * 3 + 1) * NPTS + q];
        float qz = xyz[(b * 3 + 2) * NPTS + q];
        float2 cf = CF[qb * NC + o];
        const int* ip = idxb + qb * KNN;
        float r = 0.f;
        #pragma unroll 4
        for (int kk = 0; kk < KNN; kk++) {
            int mi = ip[kk];
            float4 c = cand[b * NPTS + mi];
            float dx = qx - c.x, dy = qy - c.y, dz = qz - c.z;
            float d = sqrtf(fmaf(dx, dx, fmaf(dy, dy, dz * dz)));
            float2 gf = GF[((size_t)(b * NPTS + mi)) * NC + o];
            float gpre = cf.x + fmaf(wd, d, gf.x);
            float fpre = cf.y + gf.y;
            r = fmaxf(r, fmaxf(gpre, 0.f) * fmaxf(fpre, 0.f));
        }
        tile[(w * 4 + i) * 65 + o] = r;
    }
    __syncthreads();
    int row = tid >> 2, cg = (tid & 3) * 4;
    float* orow = out + (size_t)(b * NC + row) * NPTS + nt + cg;
    #pragma unroll
    for (int j = 0; j < 4; j++) orow[j] = tile[(cg + j) * 65 + row];
}

extern "C" void kernel_launch(void* const* d_in, const int* in_sizes, int n_in,
                              void* d_out, int out_size, void* d_ws, size_t ws_size,
                              hipStream_t stream) {
    const float* xyz   = (const float*)d_in[0];
    const float* xyz_s = (const float*)d_in[1];
    const float* fea   = (const float*)d_in[2];
    const float* fea_s = (const float*)d_in[3];
    const float* Wg    = (const float*)d_in[4];
    const float* bg    = (const float*)d_in[5];
    const float* Wf    = (const float*)d_in[6];
    const float* bf    = (const float*)d_in[7];
    float* out = (float*)d_out;

    char* ws = (char*)d_ws;
    float4* cand = (float4*)ws;                 ws += (size_t)NQ * 16;              // 512 KB
    float2* GF   = (float2*)ws;                 ws += (size_t)NQ * NC * 8;          // 16.8 MB
    float2* CF   = (float2*)ws;                 ws += (size_t)NQ * NC * 8;          // 16.8 MB
    int*    idxb = (int*)ws;                    ws += (size_t)NQ * KNN * 4;         // 2 MB
    float4* QT   = (float4*)ws;                 ws += (size_t)NQ * 16;              // 512 KB
    unsigned short* surv2 = (unsigned short*)ws; ws += (size_t)NQ * 4 * SEGCAP * 2; // 16.8 MB
    unsigned char*  cnt2  = (unsigned char*)ws;                                     // 128 KB

    prep_kernel<<<(NQ / 256) * 2, 256, 0, stream>>>(
        xyz, xyz_s, fea, fea_s, Wg, bg, Wf, bf, cand, GF, CF);
    knn_tau<<<NQ / 64, 512, 0, stream>>>(cand, xyz, QT);
    // grid = NB batches x 128 query-chunks x 4 candidate-groups = 2048 blocks
    knn_scan<<<NB * 128 * 4, 256, 0, stream>>>(cand, QT, surv2, cnt2);
    knn_select<<<NQ / 256, 256, 0, stream>>>(
        cand, QT, (const uchar4*)cnt2, surv2, idxb);
    fuse_kernel<<<NB * (NPTS / 16), 256, 0, stream>>>(
        xyz, Wg, cand, GF, CF, idxb, out);
}

// Round 13
// 253.556 us; speedup vs baseline: 1.2595x; 1.2595x over previous
//
#include <hip/hip_runtime.h>
#include <math.h>

#define NPTS 8192
#define NB   4
#define KNN  16
#define NC   64
#define NQ   (NB * NPTS)   // 32768 total queries
#define CAP2 32            // per-(wave,query) LDS survivor capacity (E~5.5)
#define CAP2P 34           // padded stride (bank spread for select reads)

// ---------------------------------------------------------------------------
// prep (2 phases as separate blocks) — unchanged (validated r2..r12):
//  phase 0 (source pts): cand[b][m]=(x,y,z,|p|^2); GF[b][m][o]=(Gk,F2)
//  phase 1 (center pts): CF[b][n][o]=(Gc+bg, F1+bf)
// ---------------------------------------------------------------------------
__global__ __launch_bounds__(256) void prep_kernel(
    const float* __restrict__ xyz, const float* __restrict__ xyz_s,
    const float* __restrict__ fea, const float* __restrict__ fea_s,
    const float* __restrict__ Wg,  const float* __restrict__ bg,
    const float* __restrict__ Wf,  const float* __restrict__ bf,
    float4* __restrict__ cand, float2* __restrict__ GF, float2* __restrict__ CF)
{
    __shared__ float wt[64 * 64];
    __shared__ float gw[3 * 64];
    __shared__ float bias2[2 * 64];
    int tid   = threadIdx.x;
    int phase = blockIdx.x & 1;
    int g     = (blockIdx.x >> 1) * 256 + tid;
    int b     = g >> 13, m = g & (NPTS - 1);

    for (int i = tid; i < 4096; i += 256) {
        int o = i >> 6, c = i & 63;
        wt[c * 64 + o] = Wf[o * 128 + (phase ? c : 64 + c)];
    }
    if (tid < 192) {
        int d = tid >> 6, o = tid & 63;
        gw[d * 64 + o] = phase ? (Wg[o * 10 + 1 + d] + Wg[o * 10 + 7 + d])
                               : (Wg[o * 10 + 4 + d] - Wg[o * 10 + 7 + d]);
    }
    if (tid < 64) {
        bias2[tid]      = phase ? bg[tid] : 0.f;
        bias2[64 + tid] = phase ? bf[tid] : 0.f;
    }
    __syncthreads();

    const float* P = phase ? xyz : xyz_s;
    const float* F = phase ? fea : fea_s;
    float x = P[(b * 3 + 0) * NPTS + m];
    float y = P[(b * 3 + 1) * NPTS + m];
    float z = P[(b * 3 + 2) * NPTS + m];
    if (!phase) cand[b * NPTS + m] = make_float4(x, y, z, x * x + y * y + z * z);

    float acc[NC];
    #pragma unroll
    for (int o = 0; o < NC; o++) acc[o] = 0.f;
    for (int c = 0; c < NC; c++) {
        float v = F[(size_t)(b * NC + c) * NPTS + m];
        const float4* w4 = (const float4*)&wt[c * 64];
        #pragma unroll
        for (int o4 = 0; o4 < 16; o4++) {
            float4 w = w4[o4];
            acc[o4*4+0] = fmaf(w.x, v, acc[o4*4+0]);
            acc[o4*4+1] = fmaf(w.y, v, acc[o4*4+1]);
            acc[o4*4+2] = fmaf(w.z, v, acc[o4*4+2]);
            acc[o4*4+3] = fmaf(w.w, v, acc[o4*4+3]);
        }
    }
    float2* O = (phase ? CF : GF) + ((size_t)(b * NPTS + m)) * NC;
    #pragma unroll
    for (int o = 0; o < NC; o++) {
        float geo = fmaf(gw[o], x, fmaf(gw[64 + o], y, gw[128 + o] * z));
        O[o] = make_float2(geo + bias2[o], acc[o] + bias2[64 + o]);
    }
}

// ---------------------------------------------------------------------------
// knn_fused2: tau + filter + select in ONE candidate-stationary kernel.
// Block = 4 waves; wave w holds candidates [2048w, 2048(w+1)) in registers,
// lane l owning the 32 CONTIGUOUS candidates base+l*32..+31 (c[32], no LDS,
// no bpermute delivery — the r12 lesson). 64 queries/block from a 1KB LDS
// table (broadcast reads).
//  A: per-lane serial max of its 32 scores (31 fmax) -> 3x shfl_xor(1,2,4)
//     8-lane reduce -> 32 sub-chunk maxima (256 cands each) covering ALL
//     8192 candidates.
//  T: tau = 16th largest of 32 maxima (r9-validated cross-lane bitonic):
//     16 disjoint sub-chunks have max >= tau -> >=16 witnesses; E[rank]~22.
//  B: re-score (bit-identical fma), ballot-prefix push into wave-private
//     LDS lists (r7-validated, zero atomics).
//  S: thread-per-query u64 sorted-insert over the LDS lists (r7/r12-
//     validated code) -> idxb directly. No QT/surv2/cnt2 globals.
// Grid: NQ/64 = 512 blocks.
// ---------------------------------------------------------------------------
__global__ __launch_bounds__(256) void knn_fused2(
    const float4* __restrict__ cand, const float* __restrict__ xyz,
    int* __restrict__ idxout)
{
    __shared__ float4 qt_lds[64];
    __shared__ float  mxs[64][33];
    __shared__ float  tauL[64];
    __shared__ unsigned short wl[4][64][CAP2P];
    __shared__ unsigned char  wcnt[4][64];

    int tid = threadIdx.x;
    int lane = tid & 63, w = tid >> 6;
    int bid = blockIdx.x;
    int b = bid >> 7;                      // 128 blocks per batch
    int qb = (bid & 127) * 64;

    if (tid < 64) {
        int q = qb + tid;
        float x = xyz[(b * 3 + 0) * NPTS + q];
        float y = xyz[(b * 3 + 1) * NPTS + q];
        float z = xyz[(b * 3 + 2) * NPTS + q];
        qt_lds[tid] = make_float4(2.f * x, 2.f * y, 2.f * z, 0.f);
    }

    const float4* cb = cand + b * NPTS;
    int cbase = (w << 11) + (lane << 5);   // this lane's 32 contiguous cands
    float4 c[32];
    #pragma unroll
    for (int s = 0; s < 32; s++) c[s] = cb[cbase + s];
    __syncthreads();

    // ---- A: sub-chunk maxima (lane-serial + 8-lane reduce) ----
    for (int qi = 0; qi < 64; ++qi) {
        float4 qt = qt_lds[qi];
        float M = fmaf(c[0].x, qt.x, fmaf(c[0].y, qt.y,
                  fmaf(c[0].z, qt.z, -c[0].w)));
        #pragma unroll
        for (int s = 1; s < 32; s++) {
            float sc = fmaf(c[s].x, qt.x, fmaf(c[s].y, qt.y,
                       fmaf(c[s].z, qt.z, -c[s].w)));
            M = fmaxf(M, sc);
        }
        float gmx = M;
        gmx = fmaxf(gmx, __shfl_xor(gmx, 1));
        gmx = fmaxf(gmx, __shfl_xor(gmx, 2));
        gmx = fmaxf(gmx, __shfl_xor(gmx, 4));   // 8-lane group max
        if ((lane & 7) == 0) mxs[qi][(w << 3) + (lane >> 3)] = gmx;
    }
    __syncthreads();

    // ---- T: tau = 16th largest of 32 sub-chunk maxima (bitonic, r9 form) --
    for (int qq = w * 16; qq < w * 16 + 16; ++qq) {
        float v = (lane < 32) ? mxs[qq][lane] : -3.0e38f;
        #pragma unroll
        for (int k = 2; k <= 64; k <<= 1) {
            #pragma unroll
            for (int j = k >> 1; j > 0; j >>= 1) {
                float o = __shfl_xor(v, j);
                bool up = ((lane & k) == 0);
                bool lower = ((lane & j) == 0);
                v = (up == lower) ? fminf(v, o) : fmaxf(v, o);
            }
        }
        float t = __shfl(v, 48);           // 16th largest (all lanes execute)
        if (lane == 0) tauL[qq] = t;
    }
    __syncthreads();

    // ---- B: filter with ballot-prefix push (zero atomics) ----
    unsigned long long lmask = (1ull << lane) - 1ull;
    for (int qi = 0; qi < 64; ++qi) {
        float4 qt = qt_lds[qi];
        float tau = tauL[qi];
        unsigned vcnt = 0;
        #pragma unroll
        for (int s = 0; s < 32; s++) {
            float sc = fmaf(c[s].x, qt.x, fmaf(c[s].y, qt.y,
                       fmaf(c[s].z, qt.z, -c[s].w)));
            bool p = (sc >= tau);
            unsigned long long mask = __ballot(p);
            if (p) {
                unsigned pos = vcnt + (unsigned)__popcll(mask & lmask);
                if (pos < CAP2)
                    wl[w][qi][pos] = (unsigned short)(cbase + s);
            }
            vcnt += (unsigned)__popcll(mask);
        }
        if (lane == 0)
            wcnt[w][qi] = (unsigned char)(vcnt < CAP2 ? vcnt : CAP2);
    }
    __syncthreads();

    // ---- S: thread-per-query top-16 select (r7/r12-validated insert) ----
    if (tid < 64) {
        int qi = tid;
        float4 qt = qt_lds[qi];
        unsigned long long s16[KNN];
        #pragma unroll
        for (int j = 0; j < KNN; j++) s16[j] = 0ull;

        for (int cgp = 0; cgp < 4; cgp++) {
            int cn = wcnt[cgp][qi];
            for (int j0 = 0; j0 < cn; j0 += 4) {
                int li[4];
                float4 cd[4];
                #pragma unroll
                for (int t = 0; t < 4; t++) {
                    int j = j0 + t;
                    li[t] = (j < cn) ? (int)wl[cgp][qi][j] : -1;
                }
                #pragma unroll
                for (int t = 0; t < 4; t++)
                    if (li[t] >= 0) cd[t] = cb[li[t]];
                #pragma unroll
                for (int t = 0; t < 4; t++) {
                    if (li[t] < 0) continue;
                    float sc = fmaf(cd[t].x, qt.x, fmaf(cd[t].y, qt.y,
                               fmaf(cd[t].z, qt.z, -cd[t].w)));
                    unsigned u = __float_as_uint(sc);
                    u ^= (unsigned)((int)u >> 31) | 0x80000000u;
                    unsigned long long key =
                        ((unsigned long long)u << 32) | (unsigned)(8191 - li[t]);
                    if (key > s16[0]) {
                        bool cj = true;
                        #pragma unroll
                        for (int t2 = 0; t2 < KNN; t2++) {
                            bool cn2 = (t2 < KNN - 1) ? (key > s16[t2 + 1]) : false;
                            unsigned long long fv = cj ? key : s16[t2];
                            s16[t2] = cn2 ? s16[t2 + 1] : fv;
                            cj = cn2;
                        }
                    }
                }
            }
        }
        int* op = idxout + (((size_t)(b * NPTS + qb + qi)) << 4);
        #pragma unroll
        for (int j = 0; j < KNN; j++)
            op[j] = 8191 - (int)(s16[j] & 0xFFFFFFFFull);
    }
}

// ---------------------------------------------------------------------------
// fuse — unchanged (validated r2..r12):
// out[b][o][n] = max_k relu(CF.x + wd*d + GF.x) * relu(CF.y + GF.y)
// ---------------------------------------------------------------------------
__global__ __launch_bounds__(256) void fuse_kernel(
    const float* __restrict__ xyz, const float* __restrict__ Wg,
    const float4* __restrict__ cand, const float2* __restrict__ GF,
    const float2* __restrict__ CF, const int* __restrict__ idxb,
    float* __restrict__ out)
{
    __shared__ float tile[16 * 65];
    int tid = threadIdx.x;
    int o = tid & 63, w = tid >> 6;
    int b = blockIdx.x >> 9;
    int nt = (blockIdx.x & 511) << 4;
    float wd = Wg[o * 10];

    for (int i = 0; i < 4; i++) {
        int q = nt + w * 4 + i;
        size_t qb = (size_t)(b * NPTS + q);
        float qx = xyz[(b * 3 + 0) * NPTS + q];
        float qy = xyz[(b * 3 + 1) * NPTS + q];
        float qz = xyz[(b * 3 + 2) * NPTS + q];
        float2 cf = CF[qb * NC + o];
        const int* ip = idxb + qb * KNN;
        float r = 0.f;
        #pragma unroll 4
        for (int kk = 0; kk < KNN; kk++) {
            int mi = ip[kk];
            float4 c = cand[b * NPTS + mi];
            float dx = qx - c.x, dy = qy - c.y, dz = qz - c.z;
            float d = sqrtf(fmaf(dx, dx, fmaf(dy, dy, dz * dz)));
            float2 gf = GF[((size_t)(b * NPTS + mi)) * NC + o];
            float gpre = cf.x + fmaf(wd, d, gf.x);
            float fpre = cf.y + gf.y;
            r = fmaxf(r, fmaxf(gpre, 0.f) * fmaxf(fpre, 0.f));
        }
        tile[(w * 4 + i) * 65 + o] = r;
    }
    __syncthreads();
    int row = tid >> 2, cg = (tid & 3) * 4;
    float* orow = out + (size_t)(b * NC + row) * NPTS + nt + cg;
    #pragma unroll
    for (int j = 0; j < 4; j++) orow[j] = tile[(cg + j) * 65 + row];
}

extern "C" void kernel_launch(void* const* d_in, const int* in_sizes, int n_in,
                              void* d_out, int out_size, void* d_ws, size_t ws_size,
                              hipStream_t stream) {
    const float* xyz   = (const float*)d_in[0];
    const float* xyz_s = (const float*)d_in[1];
    const float* fea   = (const float*)d_in[2];
    const float* fea_s = (const float*)d_in[3];
    const float* Wg    = (const float*)d_in[4];
    const float* bg    = (const float*)d_in[5];
    const float* Wf    = (const float*)d_in[6];
    const float* bf    = (const float*)d_in[7];
    float* out = (float*)d_out;

    char* ws = (char*)d_ws;
    float4* cand = (float4*)ws;                 ws += (size_t)NQ * 16;      // 512 KB
    float2* GF   = (float2*)ws;                 ws += (size_t)NQ * NC * 8;  // 16.8 MB
    float2* CF   = (float2*)ws;                 ws += (size_t)NQ * NC * 8;  // 16.8 MB
    int*    idxb = (int*)ws;                                                // 2 MB

    prep_kernel<<<(NQ / 256) * 2, 256, 0, stream>>>(
        xyz, xyz_s, fea, fea_s, Wg, bg, Wf, bf, cand, GF, CF);
    knn_fused2<<<NQ / 64, 256, 0, stream>>>(cand, xyz, idxb);
    fuse_kernel<<<NB * (NPTS / 16), 256, 0, stream>>>(
        xyz, Wg, cand, GF, CF, idxb, out);
}